// Round 1
// baseline (275.970 us; speedup 1.0000x reference)
//
#include <hip/hip_runtime.h>

#define NROWS 262144
#define HIDN 50
#define KK 10
#define TDIM 8
#define BB 3.0f

// zero the logdet accumulator slot (d_out is poisoned 0xAA before every timed launch)
__global__ void nsf_zero(float* __restrict__ p) {
    if (threadIdx.x == 0) *p = 0.0f;
}

__device__ __forceinline__ float fast_tanh(float a) {
    // tanh(a) = 1 - 2/(exp(2a)+1): monotone, saturates correctly, no NaN for large |a|
    float e = __expf(2.0f * a);
    return 1.0f - __fdividef(2.0f, e + 1.0f);
}

__global__ __launch_bounds__(256) void nsf_main(
    const float* __restrict__ x,
    const float* __restrict__ w0, const float* __restrict__ b0,
    const float* __restrict__ w1, const float* __restrict__ b1,
    const float* __restrict__ ww, const float* __restrict__ bw,
    const float* __restrict__ wh, const float* __restrict__ bh,
    const float* __restrict__ wd, const float* __restrict__ bd,
    float* __restrict__ out, float* __restrict__ ldsum_out)
{
    // per-thread h row in LDS, stride 51 (odd) -> 2-way bank alias only (free)
    __shared__ float hbuf[256 * 51];
    __shared__ float red[4];

    const int tid = threadIdx.x;
    const int r = blockIdx.x * 256 + tid;

    const float4* xv = (const float4*)x;
    const float4 xv0 = xv[r * 4 + 0];
    const float4 xv1 = xv[r * 4 + 1];
    const float4 xv2 = xv[r * 4 + 2];
    const float4 xv3 = xv[r * 4 + 3];

    // passthrough of the 8 scale dims
    float4* ov = (float4*)out;
    ov[r * 4 + 0] = xv0;
    ov[r * 4 + 1] = xv1;

    float acc[HIDN];

    // ---- phase 1: h1 = tanh(zd @ w0 + b0) ----
    #pragma unroll
    for (int j = 0; j < HIDN; ++j) acc[j] = b0[j];
    {
        const float z0[8] = {xv0.x, xv0.y, xv0.z, xv0.w, xv1.x, xv1.y, xv1.z, xv1.w};
        #pragma unroll
        for (int k = 0; k < 8; ++k) {
            const float zk = z0[k];
            #pragma unroll
            for (int j = 0; j < HIDN; ++j)
                acc[j] = fmaf(zk, w0[k * HIDN + j], acc[j]);
        }
    }
    float* hrow = &hbuf[tid * 51];
    #pragma unroll
    for (int j = 0; j < HIDN; ++j) hrow[j] = fast_tanh(acc[j]);

    // ---- phase 2: h2 = tanh(h1 @ w1 + b1) ----
    #pragma unroll
    for (int j = 0; j < HIDN; ++j) acc[j] = b1[j];
    #pragma unroll 2
    for (int k = 0; k < HIDN; ++k) {
        const float hk = hrow[k];
        #pragma unroll
        for (int j = 0; j < HIDN; ++j)
            acc[j] = fmaf(hk, w1[k * HIDN + j], acc[j]);
    }
    #pragma unroll
    for (int j = 0; j < HIDN; ++j) hrow[j] = fast_tanh(acc[j]);

    // ---- phase 3: per transformed dim ----
    float ldacc = 0.0f;
    #pragma unroll 1
    for (int d = 0; d < TDIM; ++d) {
        float aw[KK], ah[KK], ad[KK - 1];
        #pragma unroll
        for (int i = 0; i < KK; ++i)     aw[i] = bw[d * KK + i];
        #pragma unroll
        for (int i = 0; i < KK; ++i)     ah[i] = bh[d * KK + i];
        #pragma unroll
        for (int i = 0; i < KK - 1; ++i) ad[i] = bd[d * (KK - 1) + i];

        #pragma unroll 2
        for (int k = 0; k < HIDN; ++k) {
            const float hk = hrow[k];
            const float* wwr = ww + k * (TDIM * KK) + d * KK;
            const float* whr = wh + k * (TDIM * KK) + d * KK;
            const float* wdr = wd + k * (TDIM * (KK - 1)) + d * (KK - 1);
            #pragma unroll
            for (int i = 0; i < KK; ++i)     aw[i] = fmaf(hk, wwr[i], aw[i]);
            #pragma unroll
            for (int i = 0; i < KK; ++i)     ah[i] = fmaf(hk, whr[i], ah[i]);
            #pragma unroll
            for (int i = 0; i < KK - 1; ++i) ad[i] = fmaf(hk, wdr[i], ad[i]);
        }

        // softmax over K for widths (logits = 6*aw)
        float mw = aw[0];
        #pragma unroll
        for (int i = 1; i < KK; ++i) mw = fmaxf(mw, aw[i]);
        float sw = 0.0f;
        #pragma unroll
        for (int i = 0; i < KK; ++i) { aw[i] = __expf(6.0f * (aw[i] - mw)); sw += aw[i]; }
        const float invw = __fdividef(1.0f, sw);

        // softmax over K for heights
        float mh = ah[0];
        #pragma unroll
        for (int i = 1; i < KK; ++i) mh = fmaxf(mh, ah[i]);
        float sh = 0.0f;
        #pragma unroll
        for (int i = 0; i < KK; ++i) { ah[i] = __expf(6.0f * (ah[i] - mh)); sh += ah[i]; }
        const float invh = __fdividef(1.0f, sh);

        // softplus derivatives
        float sp[KK - 1];
        #pragma unroll
        for (int i = 0; i < KK - 1; ++i) {
            const float v = ad[i];
            sp[i] = fmaxf(v, 0.0f) + __logf(1.0f + __expf(-fabsf(v)));
        }

        // u for this dim (component select from regs; avoid dynamic reg-array index)
        const float4 vsel = (d < 4) ? xv2 : xv3;
        const int dd = d & 3;
        const float ud = (dd == 0) ? vsel.x : (dd == 1) ? vsel.y : (dd == 2) ? vsel.z : vsel.w;
        const float uc = fminf(fmaxf(ud, -BB), BB);
        const bool inside = (ud > -BB) && (ud < BB);

        // streaming bin search + parameter select
        // idx = last i in [0,K) with uc >= xe[i]  (== clip(count-1) of reference)
        float cw = 0.0f, ch = 0.0f;
        float xprev = -BB, yprev = -BB, dprev = 1.0f;
        float xk = -BB, yk = -BB, wk = 1.0f, hk2 = 1.0f, dk = 1.0f, dk1 = 1.0f;
        #pragma unroll
        for (int i = 0; i < KK; ++i) {
            cw += aw[i] * invw;
            ch += ah[i] * invh;
            const float xnext = fmaf(6.0f, cw, -BB);
            const float ynext = fmaf(6.0f, ch, -BB);
            const float dnext = (i == KK - 1) ? 1.0f : sp[i];
            const bool c = (i == 0) || (uc >= xprev);
            if (c) { xk = xprev; yk = yprev; wk = xnext - xprev; hk2 = ynext - yprev; dk = dprev; dk1 = dnext; }
            xprev = xnext; yprev = ynext; dprev = dnext;
        }

        // rational-quadratic spline
        const float sk = __fdividef(hk2, wk);
        const float xi = __fdividef(uc - xk, wk);
        const float om = 1.0f - xi;
        const float denom = sk + (dk1 + dk - 2.0f * sk) * xi * om;
        const float ynum = sk * xi * xi + dk * xi * om;
        const float yv = yk + hk2 * __fdividef(ynum, denom);
        const float larg = dk1 * xi * xi + 2.0f * sk * xi * om + dk * om * om;
        const float ldet = 2.0f * __logf(sk) + __logf(larg) - 2.0f * __logf(denom);

        out[r * 16 + 8 + d] = inside ? yv : ud;
        ldacc += inside ? ldet : 0.0f;
    }

    // ---- logdet reduction: wave shuffle -> LDS -> one atomic per block ----
    #pragma unroll
    for (int off = 32; off > 0; off >>= 1) ldacc += __shfl_down(ldacc, off);
    if ((tid & 63) == 0) red[tid >> 6] = ldacc;
    __syncthreads();
    if (tid == 0) atomicAdd(ldsum_out, red[0] + red[1] + red[2] + red[3]);
}

extern "C" void kernel_launch(void* const* d_in, const int* in_sizes, int n_in,
                              void* d_out, int out_size, void* d_ws, size_t ws_size,
                              hipStream_t stream) {
    const float* x  = (const float*)d_in[0];
    const float* w0 = (const float*)d_in[1];
    const float* b0 = (const float*)d_in[2];
    const float* w1 = (const float*)d_in[3];
    const float* b1 = (const float*)d_in[4];
    const float* ww = (const float*)d_in[5];
    const float* bw = (const float*)d_in[6];
    const float* wh = (const float*)d_in[7];
    const float* bh = (const float*)d_in[8];
    const float* wd = (const float*)d_in[9];
    const float* bd = (const float*)d_in[10];

    float* out = (float*)d_out;
    float* ldp = out + (size_t)NROWS * 16;  // scalar logdet sum slot

    hipLaunchKernelGGL(nsf_zero, dim3(1), dim3(64), 0, stream, ldp);
    hipLaunchKernelGGL(nsf_main, dim3(NROWS / 256), dim3(256), 0, stream,
                       x, w0, b0, w1, b1, ww, bw, wh, bh, wd, bd, out, ldp);
}